// Round 5
// baseline (307.418 us; speedup 1.0000x reference)
//
#include <hip/hip_runtime.h>

#define BB 128
#define TT 2048
#define II 32
#define HH 64

typedef __attribute__((ext_vector_type(8))) short bf16x8;
typedef __attribute__((ext_vector_type(4))) float f32x4;

__device__ __forceinline__ unsigned f2bf(float f) {
    unsigned u = __builtin_bit_cast(unsigned, f);
    return (u + 0x7fffu + ((u >> 16) & 1u)) >> 16;   // RNE truncation to bf16
}

// Swizzled float-index into xwsh[8][1024] (one t-half).  Same XOR family as
// the R2-verified swz() (0 measured conflicts), adapted to 1024-wide rows.
// Bijective: bits 7-9 of t unchanged -> XOR constant recoverable.
__device__ __forceinline__ int swz10(int r, int t) {
    return ((r << 10) + t) ^ (((t >> 5) & 31) << 2);
}

// ---- scan sequence macros over locals q0..q7 (time order / reversed) -------
#define FWD_SEQ(M) \
  M(q0.x) M(q0.y) M(q0.z) M(q0.w) M(q1.x) M(q1.y) M(q1.z) M(q1.w) \
  M(q2.x) M(q2.y) M(q2.z) M(q2.w) M(q3.x) M(q3.y) M(q3.z) M(q3.w) \
  M(q4.x) M(q4.y) M(q4.z) M(q4.w) M(q5.x) M(q5.y) M(q5.z) M(q5.w) \
  M(q6.x) M(q6.y) M(q6.z) M(q6.w) M(q7.x) M(q7.y) M(q7.z) M(q7.w)
#define BWD_SEQ(M) \
  M(q7.w) M(q7.z) M(q7.y) M(q7.x) M(q6.w) M(q6.z) M(q6.y) M(q6.x) \
  M(q5.w) M(q5.z) M(q5.y) M(q5.x) M(q4.w) M(q4.z) M(q4.y) M(q4.x) \
  M(q3.w) M(q3.z) M(q3.y) M(q3.x) M(q2.w) M(q2.z) M(q2.y) M(q2.x) \
  M(q1.w) M(q1.z) M(q1.y) M(q1.x) M(q0.w) M(q0.z) M(q0.y) M(q0.x)

// ---- general-W fallback: serial chain, one wave per (dir,b) ----------------
template<int DIR>
__device__ __noinline__ void rnn_serial_f(
    const float* __restrict__ Wih, const float* __restrict__ bih,
    const float* __restrict__ bhh, const float* __restrict__ Whh,
    const float* __restrict__ x, unsigned short* __restrict__ hbuf,
    int b, int lane, float (*hs)[HH])
{
    const float bias = bih[lane] + bhh[lane];
    const float4* wip = (const float4*)(Wih + lane * II);
    const float4* whp = (const float4*)(Whh + lane * HH);
    hs[0][lane] = 0.0f;
    unsigned short* hb = hbuf + ((size_t)(DIR * BB + b) * HH + lane) * TT;
    int cur = 0;
    for (int s = 0; s < TT; ++s) {
        const int t = DIR ? (TT - 1 - s) : s;
        const float4* xr = (const float4*)(x + ((size_t)b * TT + t) * II);
        float a0 = bias, a1 = 0.f, a2 = 0.f, a3 = 0.f;
        #pragma unroll
        for (int i4 = 0; i4 < II / 4; ++i4) {
            const float4 w4 = wip[i4];
            const float4 v  = xr[i4];
            a0 = fmaf(w4.x, v.x, a0); a1 = fmaf(w4.y, v.y, a1);
            a2 = fmaf(w4.z, v.z, a2); a3 = fmaf(w4.w, v.w, a3);
        }
        float s0 = 0.f, s1 = 0.f, s2 = 0.f, s3 = 0.f;
        const float* hc = hs[cur];
        #pragma unroll
        for (int j4 = 0; j4 < HH / 4; ++j4) {
            const float4 w4 = whp[j4];
            const float4 h4 = *(const float4*)(hc + 4 * j4);
            s0 = fmaf(w4.x, h4.x, s0); s1 = fmaf(w4.y, h4.y, s1);
            s2 = fmaf(w4.z, h4.z, s2); s3 = fmaf(w4.w, h4.w, s3);
        }
        const float h = fmaxf((a0 + a1) + (a2 + a3) + ((s0 + s1) + (s2 + s3)), 0.0f);
        hs[cur ^ 1][lane] = h;
        hb[t] = (unsigned short)f2bf(h);
        cur ^= 1;
    }
}

// ---- fused proj+rnn, v2: coalesced x via LDS chunk staging -----------------
// Block = (b, 8 rows = 4f + 4b), 512 thr / 8 waves, grid 16 g x 128 b
// (b-fast: the 16 blocks sharing x[b] land on one XCD, x working set/XCD = 4MB = L2).
// Per t-half (1024 t):
//   8 chunks of 128 t: coalesced x load (2 dwordx4/thr) -> f4-XOR-swizzled
//   LDS stage -> threads 0..255 compute 1 t x 4 rows (wave-uniform W scalar
//   loads, SAME fma chains as R2 -> bit-identical xw) -> swizzled xwsh[8][1024].
//   After half h: lanes (l>>5)==h snapshot their q0..q7 (lane l owns t [32l,32l+32)).
// Scan/apply/store: byte-identical to R2 (verified).
__global__ __launch_bounds__(512, 4) void rnn_fused_kernel(
    const float* __restrict__ x,
    const float* __restrict__ Wf, const float* __restrict__ bihf, const float* __restrict__ bhhf,
    const float* __restrict__ Wb, const float* __restrict__ bihb, const float* __restrict__ bhhb,
    const float* __restrict__ Whf, const float* __restrict__ Whb,
    unsigned short* __restrict__ hbuf)
{
    __shared__ __align__(16) float xwsh[8 * 1024];      // 32 KB: one t-half
    __shared__ __align__(16) float xst[128 * 32];       // 16 KB: x chunk, f4-swizzled
    __shared__ float sflags[2];
    __shared__ __align__(16) float hshd[2][2][HH];      // serial fallback bufs

    const int tid  = threadIdx.x;
    const int lane = tid & 63;
    const int wv   = __builtin_amdgcn_readfirstlane(tid >> 6);  // 0..7
    const int blk  = blockIdx.x;
    const int b    = blk & (BB - 1);
    const int g    = blk >> 7;           // 0..15 -> hrows [4g, 4g+4)

    // ---- W_hh == I check (waves 0/1), flags to LDS ----
    if (wv < 2) {
        const float* W = wv ? Whb : Whf;
        bool ok = true;
        const float4* wp = (const float4*)(W + lane * HH);
        #pragma unroll
        for (int j4 = 0; j4 < HH / 4; ++j4) {
            float4 v = wp[j4];
            ok &= (v.x == ((4*j4+0 == lane) ? 1.0f : 0.0f));
            ok &= (v.y == ((4*j4+1 == lane) ? 1.0f : 0.0f));
            ok &= (v.z == ((4*j4+2 == lane) ? 1.0f : 0.0f));
            ok &= (v.w == ((4*j4+3 == lane) ? 1.0f : 0.0f));
        }
        const bool isI = (__ballot(ok) == ~0ull);
        if (lane == 0) sflags[wv] = isI ? 1.0f : 0.0f;
    }
    __syncthreads();
    const bool iF = sflags[0] != 0.0f;
    const bool iB = sflags[1] != 0.0f;

    float4 q0 = {0,0,0,0}, q1 = {0,0,0,0}, q2 = {0,0,0,0}, q3 = {0,0,0,0},
           q4 = {0,0,0,0}, q5 = {0,0,0,0}, q6 = {0,0,0,0}, q7 = {0,0,0,0};

    if (iF | iB) {
        // compute-role constants (threads 0..255; one t x 4 rows of one dir)
        const int crow0     = (tid >> 7) << 2;       // 0 (dir0) or 4 (dir1)
        const int ct        = tid & 127;             // t within chunk
        const bool isComp   = (tid < 256);
        const bool cEn      = (crow0 == 0) ? iF : iB;

        const float* wrp[4];
        float brow[4];
        {
            const int dr = crow0 >> 2;
            #pragma unroll
            for (int rr = 0; rr < 4; ++rr) {
                const int hr = g * 4 + rr;
                wrp[rr]  = (dr ? Wb : Wf) + hr * II;
                brow[rr] = dr ? (bihb[hr] + bhhb[hr]) : (bihf[hr] + bhhf[hr]);
            }
        }

        #pragma unroll 1
        for (int half = 0; half < 2; ++half) {
            #pragma unroll 1
            for (int c = 0; c < 8; ++c) {
                // ---- stage chunk: coalesced, f4-XOR-swizzled LDS write ----
                {
                    const float4* g4 = (const float4*)(x +
                        ((size_t)b * TT + (half << 10) + (c << 7)) * II);
                    const float4 v0 = g4[tid];
                    const float4 v1 = g4[tid + 512];
                    const int p0 = (tid & ~7) | ((tid & 7) ^ ((tid >> 3) & 7));
                    const int qq = tid + 512;
                    const int p1 = (qq & ~7) | ((qq & 7) ^ ((qq >> 3) & 7));
                    *(float4*)&xst[p0 << 2] = v0;
                    *(float4*)&xst[p1 << 2] = v1;
                }
                __syncthreads();
                // ---- compute: 1 t x 4 rows per thread (threads 0..255) ----
                if (isComp && cEn) {
                    #define LDX(i) (*(const float4*)&xst[(((ct) << 3) | ((i) ^ ((ct) & 7))) << 2])
                    const float4 x0 = LDX(0), x1 = LDX(1), x2 = LDX(2), x3 = LDX(3),
                                 x4 = LDX(4), x5 = LDX(5), x6 = LDX(6), x7 = LDX(7);
                    #undef LDX
                    const int th = (c << 7) + ct;     // t within half
                    #pragma unroll
                    for (int rr = 0; rr < 4; ++rr) {
                        const float* wr = wrp[rr];
                        float a0 = brow[rr], a1 = 0.f, a2 = 0.f, a3 = 0.f;
                        #define G(gq, xg) \
                            a0 = fmaf(wr[4*gq+0], xg.x, a0); a1 = fmaf(wr[4*gq+1], xg.y, a1); \
                            a2 = fmaf(wr[4*gq+2], xg.z, a2); a3 = fmaf(wr[4*gq+3], xg.w, a3);
                        G(0,x0) G(1,x1) G(2,x2) G(3,x3) G(4,x4) G(5,x5) G(6,x6) G(7,x7)
                        #undef G
                        xwsh[swz10(crow0 + rr, th)] = (a0 + a1) + (a2 + a3);
                    }
                }
                __syncthreads();
            }
            // ---- q snapshot for the lanes owning this half ----
            if ((lane >> 5) == half) {
                const int tb = (lane & 31) << 5;      // t within half
                q0 = *(const float4*)(xwsh + swz10(wv, tb + 0));
                q1 = *(const float4*)(xwsh + swz10(wv, tb + 4));
                q2 = *(const float4*)(xwsh + swz10(wv, tb + 8));
                q3 = *(const float4*)(xwsh + swz10(wv, tb + 12));
                q4 = *(const float4*)(xwsh + swz10(wv, tb + 16));
                q5 = *(const float4*)(xwsh + swz10(wv, tb + 20));
                q6 = *(const float4*)(xwsh + swz10(wv, tb + 24));
                q7 = *(const float4*)(xwsh + swz10(wv, tb + 28));
            }
            __syncthreads();   // protect xwsh before next half overwrites
        }

        // ---- scan: byte-identical to R2 (verified) ----
        const int dir  = wv >> 2;
        const int hrow = g * 4 + (wv & 3);
        const bool en  = dir ? iB : iF;
        if (en) {
            float A = 0.0f, Bv = -__builtin_inff();
            #define CSTEP(c) { A = A + (c); Bv = fmaxf(Bv + (c), 0.0f); }
            if (dir == 0) { FWD_SEQ(CSTEP) } else { BWD_SEQ(CSTEP) }
            #undef CSTEP

            float h;
            if (dir == 0) {
                #pragma unroll
                for (int off = 1; off < 64; off <<= 1) {
                    float Au = __shfl_up(A,  (unsigned)off);
                    float Bu = __shfl_up(Bv, (unsigned)off);
                    if (lane >= off) {
                        Bv = fmaxf(Bu + A, Bv);
                        A  = Au + A;
                    }
                }
                float Ae = __shfl_up(A, 1u);
                float Be = __shfl_up(Bv, 1u);
                h = (lane == 0) ? 0.0f : fmaxf(Ae, Be);
            } else {
                #pragma unroll
                for (int off = 1; off < 64; off <<= 1) {
                    float Au = __shfl_down(A,  (unsigned)off);
                    float Bu = __shfl_down(Bv, (unsigned)off);
                    if (lane < 64 - off) {
                        Bv = fmaxf(Bu + A, Bv);
                        A  = Au + A;
                    }
                }
                float Ae = __shfl_down(A, 1u);
                float Be = __shfl_down(Bv, 1u);
                h = (lane == 63) ? 0.0f : fmaxf(Ae, Be);
            }

            #define ASTEP(c) { h = fmaxf(h + (c), 0.0f); (c) = h; }
            if (dir == 0) { FWD_SEQ(ASTEP) } else { BWD_SEQ(ASTEP) }
            #undef ASTEP

            // pack to bf16, 64B/lane store (global t base = lane*32)
            unsigned short* hb = hbuf + ((size_t)(dir * BB + b) * HH + hrow) * TT + (lane << 5);
            uint4 s0q, s1q, s2q, s3q;
            s0q.x = f2bf(q0.x) | (f2bf(q0.y) << 16); s0q.y = f2bf(q0.z) | (f2bf(q0.w) << 16);
            s0q.z = f2bf(q1.x) | (f2bf(q1.y) << 16); s0q.w = f2bf(q1.z) | (f2bf(q1.w) << 16);
            s1q.x = f2bf(q2.x) | (f2bf(q2.y) << 16); s1q.y = f2bf(q2.z) | (f2bf(q2.w) << 16);
            s1q.z = f2bf(q3.x) | (f2bf(q3.y) << 16); s1q.w = f2bf(q3.z) | (f2bf(q3.w) << 16);
            s2q.x = f2bf(q4.x) | (f2bf(q4.y) << 16); s2q.y = f2bf(q4.z) | (f2bf(q4.w) << 16);
            s2q.z = f2bf(q5.x) | (f2bf(q5.y) << 16); s2q.w = f2bf(q5.z) | (f2bf(q5.w) << 16);
            s3q.x = f2bf(q6.x) | (f2bf(q6.y) << 16); s3q.y = f2bf(q6.z) | (f2bf(q6.w) << 16);
            s3q.z = f2bf(q7.x) | (f2bf(q7.y) << 16); s3q.w = f2bf(q7.z) | (f2bf(q7.w) << 16);
            uint4* hv = (uint4*)hb;
            hv[0] = s0q; hv[1] = s1q; hv[2] = s2q; hv[3] = s3q;
        }
    }

    // ---- non-identity fallback (one serial wave per dir, block g==0) ----
    if (!iF && g == 0 && wv == 0)
        rnn_serial_f<0>(Wf, bihf, bhhf, Whf, x, hbuf, b, lane, hshd[0]);
    if (!iB && g == 0 && wv == 1)
        rnn_serial_f<1>(Wb, bihb, bhhb, Whb, x, hbuf, b, lane, hshd[1]);
}

// ---------------- mlp: bf16 MFMA GEMM, LDS-staged B operand (R4, unchanged) --
__global__ __launch_bounds__(256) void mlp_kernel(
    const unsigned short* __restrict__ hbuf,
    const float* __restrict__ w0, const float* __restrict__ b0,
    const float* __restrict__ w1, const float* __restrict__ b1,
    float* __restrict__ out)
{
    const int tid  = threadIdx.x;
    const int lane = tid & 63;
    const int wv   = tid >> 6;            // 0..3
    const int blk  = blockIdx.x;          // 0..4095
    const int b    = blk >> 5;
    const int t0   = (blk & 31) << 6;     // 64 t per block

    __shared__ __align__(16) unsigned short w0sh[32 * 64 * 8];   // 32 KB
    __shared__ __align__(16) unsigned int   hsh[128 * 32];       // 16 KB (bf16 [128][64], dw-swizzled)

    // ---- stage w0 in A-fragment order ----
    #pragma unroll
    for (int it = 0; it < 8; ++it) {
        const int c  = it * 256 + tid;     // chunk = (frag, lane)
        const int f  = c >> 6, l = c & 63;
        const int kt = f >> 2, jt = f & 3;
        const int krow = kt * 16 + (l & 15);
        const int j0   = jt * 32 + ((l >> 4) << 3);
        const float4* wp = (const float4*)(w0 + krow * 128 + j0);
        const float4 a = wp[0], bq = wp[1];
        uint4 pk;
        pk.x = f2bf(a.x)  | (f2bf(a.y)  << 16);
        pk.y = f2bf(a.z)  | (f2bf(a.w)  << 16);
        pk.z = f2bf(bq.x) | (f2bf(bq.y) << 16);
        pk.w = f2bf(bq.z) | (f2bf(bq.w) << 16);
        *(uint4*)(w0sh + (size_t)c * 8) = pk;
    }

    // ---- stage h tile: 4 coalesced uint4 per thread ----
    #pragma unroll
    for (int it = 0; it < 4; ++it) {
        const int q   = it * 256 + tid;
        const int j   = q >> 3, sub = q & 7;
        const unsigned short* rp =
            hbuf + ((size_t)((j >> 6) * BB + b) * HH + (j & 63)) * TT + t0;
        const uint4 v = *(const uint4*)(rp + sub * 8);
        const int dwb = j * 32 + sub * 4;
        *(uint4*)(hsh + (dwb ^ (((j >> 3) & 3) << 3))) = v;
    }
    __syncthreads();

    const int lg = lane >> 4;                      // k-group 0..3
    const int tl = (wv << 4) + (lane & 15);        // t within tile
    const int t  = t0 + tl;                        // output column

    f32x4 acc[8];
    #pragma unroll
    for (int kt = 0; kt < 8; ++kt) {
        const float4 v = *(const float4*)(b0 + kt * 16 + lg * 4);
        acc[kt][0] = v.x; acc[kt][1] = v.y; acc[kt][2] = v.z; acc[kt][3] = v.w;
    }

    const unsigned short* hus = (const unsigned short*)hsh;
    #pragma unroll
    for (int jt = 0; jt < 4; ++jt) {
        bf16x8 bf;
        #pragma unroll
        for (int i = 0; i < 8; ++i) {
            const int j  = jt * 32 + lg * 8 + i;
            const int dw = (j * 32 + (tl >> 1)) ^ (lg << 3);
            bf[i] = (short)hus[dw * 2 + (tl & 1)];
        }
        #pragma unroll
        for (int kt = 0; kt < 8; ++kt) {
            const bf16x8 af = *(const bf16x8*)(w0sh + (size_t)((kt * 4 + jt) * 64 + lane) * 8);
            acc[kt] = __builtin_amdgcn_mfma_f32_16x16x32_bf16(af, bf, acc[kt], 0, 0, 0);
        }
    }

    float o = 0.0f;
    #pragma unroll
    for (int kt = 0; kt < 8; ++kt) {
        const float4 wq = *(const float4*)(w1 + kt * 16 + lg * 4);
        float v0 = acc[kt][0]; v0 = fmaxf(v0, 0.01f * v0); o = fmaf(v0, wq.x, o);
        float v1 = acc[kt][1]; v1 = fmaxf(v1, 0.01f * v1); o = fmaf(v1, wq.y, o);
        float v2 = acc[kt][2]; v2 = fmaxf(v2, 0.01f * v2); o = fmaf(v2, wq.z, o);
        float v3 = acc[kt][3]; v3 = fmaxf(v3, 0.01f * v3); o = fmaf(v3, wq.w, o);
    }
    o += __shfl_xor(o, 16);
    o += __shfl_xor(o, 32);
    if (lg == 0) out[(size_t)b * TT + t] = o + b1[0];
}

extern "C" void kernel_launch(void* const* d_in, const int* in_sizes, int n_in,
                              void* d_out, int out_size, void* d_ws, size_t ws_size,
                              hipStream_t stream) {
    (void)in_sizes; (void)n_in; (void)out_size; (void)ws_size;
    const float* x    = (const float*)d_in[0];
    const float* Wihf = (const float*)d_in[1];
    const float* Whhf = (const float*)d_in[2];
    const float* bihf = (const float*)d_in[3];
    const float* bhhf = (const float*)d_in[4];
    const float* Wihb = (const float*)d_in[5];
    const float* Whhb = (const float*)d_in[6];
    const float* bihb = (const float*)d_in[7];
    const float* bhhb = (const float*)d_in[8];
    const float* ff0w = (const float*)d_in[9];
    const float* ff0b = (const float*)d_in[10];
    const float* ff1w = (const float*)d_in[11];
    const float* ff1b = (const float*)d_in[12];
    unsigned short* hbuf = (unsigned short*)d_ws;   // [2][BB][HH][TT] bf16, 67 MB

    rnn_fused_kernel<<<dim3(16 * BB), dim3(512), 0, stream>>>(
        x, Wihf, bihf, bhhf, Wihb, bihb, bhhb, Whhf, Whhb, hbuf);
    mlp_kernel<<<dim3(BB * (TT / 64)), dim3(256), 0, stream>>>(
        hbuf, ff0w, ff0b, ff1w, ff1b, (float*)d_out);
}

// Round 6
// 208.895 us; speedup vs baseline: 1.4716x; 1.4716x over previous
//
#include <hip/hip_runtime.h>

#define BB 128
#define TT 2048
#define II 32
#define HH 64

typedef __attribute__((ext_vector_type(8))) short bf16x8;
typedef __attribute__((ext_vector_type(4))) float f32x4;

__device__ __forceinline__ unsigned f2bf(float f) {
    unsigned u = __builtin_bit_cast(unsigned, f);
    return (u + 0x7fffu + ((u >> 16) & 1u)) >> 16;   // RNE truncation to bf16
}

// Swizzled float-index into xwsh[8][TT].  R2-verified: 0 LDS bank conflicts.
__device__ __forceinline__ int swz(int r, int t) {
    return ((r << 11) + t) ^ (((t >> 5) & 31) << 2);
}

// ---- scan sequence macros over locals q0..q7 (time order / reversed) -------
#define FWD_SEQ(M) \
  M(q0.x) M(q0.y) M(q0.z) M(q0.w) M(q1.x) M(q1.y) M(q1.z) M(q1.w) \
  M(q2.x) M(q2.y) M(q2.z) M(q2.w) M(q3.x) M(q3.y) M(q3.z) M(q3.w) \
  M(q4.x) M(q4.y) M(q4.z) M(q4.w) M(q5.x) M(q5.y) M(q5.z) M(q5.w) \
  M(q6.x) M(q6.y) M(q6.z) M(q6.w) M(q7.x) M(q7.y) M(q7.z) M(q7.w)
#define BWD_SEQ(M) \
  M(q7.w) M(q7.z) M(q7.y) M(q7.x) M(q6.w) M(q6.z) M(q6.y) M(q6.x) \
  M(q5.w) M(q5.z) M(q5.y) M(q5.x) M(q4.w) M(q4.z) M(q4.y) M(q4.x) \
  M(q3.w) M(q3.z) M(q3.y) M(q3.x) M(q2.w) M(q2.z) M(q2.y) M(q2.x) \
  M(q1.w) M(q1.z) M(q1.y) M(q1.x) M(q0.w) M(q0.z) M(q0.y) M(q0.x)

// ---- general-W fallback: serial chain, one wave per (dir,b) ----------------
template<int DIR>
__device__ __noinline__ void rnn_serial_f(
    const float* __restrict__ Wih, const float* __restrict__ bih,
    const float* __restrict__ bhh, const float* __restrict__ Whh,
    const float* __restrict__ x, unsigned short* __restrict__ hbuf,
    int b, int lane, float (*hs)[HH])
{
    const float bias = bih[lane] + bhh[lane];
    const float4* wip = (const float4*)(Wih + lane * II);
    const float4* whp = (const float4*)(Whh + lane * HH);
    hs[0][lane] = 0.0f;
    unsigned short* hb = hbuf + ((size_t)(DIR * BB + b) * HH + lane) * TT;
    int cur = 0;
    for (int s = 0; s < TT; ++s) {
        const int t = DIR ? (TT - 1 - s) : s;
        const float4* xr = (const float4*)(x + ((size_t)b * TT + t) * II);
        float a0 = bias, a1 = 0.f, a2 = 0.f, a3 = 0.f;
        #pragma unroll
        for (int i4 = 0; i4 < II / 4; ++i4) {
            const float4 w4 = wip[i4];
            const float4 v  = xr[i4];
            a0 = fmaf(w4.x, v.x, a0); a1 = fmaf(w4.y, v.y, a1);
            a2 = fmaf(w4.z, v.z, a2); a3 = fmaf(w4.w, v.w, a3);
        }
        float s0 = 0.f, s1 = 0.f, s2 = 0.f, s3 = 0.f;
        const float* hc = hs[cur];
        #pragma unroll
        for (int j4 = 0; j4 < HH / 4; ++j4) {
            const float4 w4 = whp[j4];
            const float4 h4 = *(const float4*)(hc + 4 * j4);
            s0 = fmaf(w4.x, h4.x, s0); s1 = fmaf(w4.y, h4.y, s1);
            s2 = fmaf(w4.z, h4.z, s2); s3 = fmaf(w4.w, h4.w, s3);
        }
        const float h = fmaxf((a0 + a1) + (a2 + a3) + ((s0 + s1) + (s2 + s3)), 0.0f);
        hs[cur ^ 1][lane] = h;
        hb[t] = (unsigned short)f2bf(h);
        cur ^= 1;
    }
}

// ---- fused proj+rnn (R2/R4 structure; ONLY change: XCD-chunked block remap) -
// Old order: b = blk&127 (b fast) -> the 16 blocks sharing x[b] are 128 slots
// apart; an XCD's ~64 concurrent blocks span 64 distinct b = 16 MB >> 4 MB L2
// -> x re-fetched 3.3x from HBM (measured FETCH 111 MB).
// New order: xcd = blk&7, rank = blk>>3, b = (rank>>4)*8+xcd, g = rank&15.
// All 16 g-blocks of a b are temporally adjacent on ONE XCD; per-XCD live
// working set ~4 b x 256 KB = 1 MB < L2 -> x fetched once.  Bijective; math
// bit-identical.
__global__ __launch_bounds__(512, 4) void rnn_fused_kernel(
    const float* __restrict__ x,
    const float* __restrict__ Wf, const float* __restrict__ bihf, const float* __restrict__ bhhf,
    const float* __restrict__ Wb, const float* __restrict__ bihb, const float* __restrict__ bhhb,
    const float* __restrict__ Whf, const float* __restrict__ Whb,
    unsigned short* __restrict__ hbuf)
{
    __shared__ __align__(16) float xwsh[8 * TT];        // 64 KB
    __shared__ float sflags[2];
    __shared__ __align__(16) float hshd[2][2][HH];      // serial fallback bufs

    const int tid  = threadIdx.x;
    const int lane = tid & 63;
    const int wv   = __builtin_amdgcn_readfirstlane(tid >> 6);  // 0..7
    const int blk  = blockIdx.x;
    const int xcd  = blk & 7;
    const int rank = blk >> 3;
    const int b    = ((rank >> 4) << 3) | xcd;
    const int g    = rank & 15;          // 0..15 -> hrows [4g, 4g+4)

    // ---- W_hh == I check (waves 0/1), flags to LDS ----
    if (wv < 2) {
        const float* W = wv ? Whb : Whf;
        bool ok = true;
        const float4* wp = (const float4*)(W + lane * HH);
        #pragma unroll
        for (int j4 = 0; j4 < HH / 4; ++j4) {
            float4 v = wp[j4];
            ok &= (v.x == ((4*j4+0 == lane) ? 1.0f : 0.0f));
            ok &= (v.y == ((4*j4+1 == lane) ? 1.0f : 0.0f));
            ok &= (v.z == ((4*j4+2 == lane) ? 1.0f : 0.0f));
            ok &= (v.w == ((4*j4+3 == lane) ? 1.0f : 0.0f));
        }
        const bool isI = (__ballot(ok) == ~0ull);
        if (lane == 0) sflags[wv] = isI ? 1.0f : 0.0f;
    }
    __syncthreads();
    const bool iF = sflags[0] != 0.0f;
    const bool iB = sflags[1] != 0.0f;

    // ---- phase 1: xw into LDS ----
    if (iF | iB) {
        const int hb4 = g * 4;
        #pragma unroll 2
        for (int k = 0; k < 4; ++k) {
            const int t = tid + k * 512;
            const float4* xp = (const float4*)(x + ((size_t)b * TT + t) * II);
            const float4 x0 = xp[0], x1 = xp[1], x2 = xp[2], x3 = xp[3],
                         x4 = xp[4], x5 = xp[5], x6 = xp[6], x7 = xp[7];
            #pragma unroll
            for (int r = 0; r < 8; ++r) {
                const bool en = (r < 4) ? iF : iB;
                if (!en) continue;
                const int hr = hb4 + (r & 3);
                const float* wr   = (r < 4) ? (Wf + hr * II) : (Wb + hr * II);
                const float bias  = (r < 4) ? (bihf[hr] + bhhf[hr])
                                            : (bihb[hr] + bhhb[hr]);
                float a0 = bias, a1 = 0.f, a2 = 0.f, a3 = 0.f;
                #define G(gq, xg) \
                    a0 = fmaf(wr[4*gq+0], xg.x, a0); a1 = fmaf(wr[4*gq+1], xg.y, a1); \
                    a2 = fmaf(wr[4*gq+2], xg.z, a2); a3 = fmaf(wr[4*gq+3], xg.w, a3);
                G(0,x0) G(1,x1) G(2,x2) G(3,x3) G(4,x4) G(5,x5) G(6,x6) G(7,x7)
                #undef G
                xwsh[swz(r, t)] = (a0 + a1) + (a2 + a3);
            }
        }
    }
    __syncthreads();

    // ---- phase 2: one wave per row, associative scan ----
    const int dir  = wv >> 2;
    const int hrow = g * 4 + (wv & 3);
    const bool en  = dir ? iB : iF;
    if (en) {
        const int tb = lane << 5;           // this lane's t-segment base
        float4 q0 = *(const float4*)(xwsh + swz(wv, tb + 0));
        float4 q1 = *(const float4*)(xwsh + swz(wv, tb + 4));
        float4 q2 = *(const float4*)(xwsh + swz(wv, tb + 8));
        float4 q3 = *(const float4*)(xwsh + swz(wv, tb + 12));
        float4 q4 = *(const float4*)(xwsh + swz(wv, tb + 16));
        float4 q5 = *(const float4*)(xwsh + swz(wv, tb + 20));
        float4 q6 = *(const float4*)(xwsh + swz(wv, tb + 24));
        float4 q7 = *(const float4*)(xwsh + swz(wv, tb + 28));

        float A = 0.0f, Bv = -__builtin_inff();
        #define CSTEP(c) { A = A + (c); Bv = fmaxf(Bv + (c), 0.0f); }
        if (dir == 0) { FWD_SEQ(CSTEP) } else { BWD_SEQ(CSTEP) }
        #undef CSTEP

        float h;
        if (dir == 0) {
            #pragma unroll
            for (int off = 1; off < 64; off <<= 1) {
                float Au = __shfl_up(A,  (unsigned)off);
                float Bu = __shfl_up(Bv, (unsigned)off);
                if (lane >= off) {
                    Bv = fmaxf(Bu + A, Bv);
                    A  = Au + A;
                }
            }
            float Ae = __shfl_up(A, 1u);
            float Be = __shfl_up(Bv, 1u);
            h = (lane == 0) ? 0.0f : fmaxf(Ae, Be);
        } else {
            #pragma unroll
            for (int off = 1; off < 64; off <<= 1) {
                float Au = __shfl_down(A,  (unsigned)off);
                float Bu = __shfl_down(Bv, (unsigned)off);
                if (lane < 64 - off) {
                    Bv = fmaxf(Bu + A, Bv);
                    A  = Au + A;
                }
            }
            float Ae = __shfl_down(A, 1u);
            float Be = __shfl_down(Bv, 1u);
            h = (lane == 63) ? 0.0f : fmaxf(Ae, Be);
        }

        #define ASTEP(c) { h = fmaxf(h + (c), 0.0f); (c) = h; }
        if (dir == 0) { FWD_SEQ(ASTEP) } else { BWD_SEQ(ASTEP) }
        #undef ASTEP

        // pack to bf16, 64B/lane store
        unsigned short* hb = hbuf + ((size_t)(dir * BB + b) * HH + hrow) * TT + tb;
        uint4 s0q, s1q, s2q, s3q;
        s0q.x = f2bf(q0.x) | (f2bf(q0.y) << 16); s0q.y = f2bf(q0.z) | (f2bf(q0.w) << 16);
        s0q.z = f2bf(q1.x) | (f2bf(q1.y) << 16); s0q.w = f2bf(q1.z) | (f2bf(q1.w) << 16);
        s1q.x = f2bf(q2.x) | (f2bf(q2.y) << 16); s1q.y = f2bf(q2.z) | (f2bf(q2.w) << 16);
        s1q.z = f2bf(q3.x) | (f2bf(q3.y) << 16); s1q.w = f2bf(q3.z) | (f2bf(q3.w) << 16);
        s2q.x = f2bf(q4.x) | (f2bf(q4.y) << 16); s2q.y = f2bf(q4.z) | (f2bf(q4.w) << 16);
        s2q.z = f2bf(q5.x) | (f2bf(q5.y) << 16); s2q.w = f2bf(q5.z) | (f2bf(q5.w) << 16);
        s3q.x = f2bf(q6.x) | (f2bf(q6.y) << 16); s3q.y = f2bf(q6.z) | (f2bf(q6.w) << 16);
        s3q.z = f2bf(q7.x) | (f2bf(q7.y) << 16); s3q.w = f2bf(q7.z) | (f2bf(q7.w) << 16);
        uint4* hv = (uint4*)hb;
        hv[0] = s0q; hv[1] = s1q; hv[2] = s2q; hv[3] = s3q;
    }

    // ---- non-identity fallback (one serial wave per dir, block g==0) ----
    if (!iF && g == 0 && wv == 0)
        rnn_serial_f<0>(Wf, bihf, bhhf, Whf, x, hbuf, b, lane, hshd[0]);
    if (!iB && g == 0 && wv == 1)
        rnn_serial_f<1>(Wb, bihb, bhhb, Whb, x, hbuf, b, lane, hshd[1]);
}

// ---------------- mlp: bf16 MFMA GEMM, LDS-staged B operand (R4, unchanged) --
__global__ __launch_bounds__(256) void mlp_kernel(
    const unsigned short* __restrict__ hbuf,
    const float* __restrict__ w0, const float* __restrict__ b0,
    const float* __restrict__ w1, const float* __restrict__ b1,
    float* __restrict__ out)
{
    const int tid  = threadIdx.x;
    const int lane = tid & 63;
    const int wv   = tid >> 6;            // 0..3
    const int blk  = blockIdx.x;          // 0..4095
    const int b    = blk >> 5;
    const int t0   = (blk & 31) << 6;     // 64 t per block

    __shared__ __align__(16) unsigned short w0sh[32 * 64 * 8];   // 32 KB
    __shared__ __align__(16) unsigned int   hsh[128 * 32];       // 16 KB (bf16 [128][64], dw-swizzled)

    // ---- stage w0 in A-fragment order ----
    #pragma unroll
    for (int it = 0; it < 8; ++it) {
        const int c  = it * 256 + tid;     // chunk = (frag, lane)
        const int f  = c >> 6, l = c & 63;
        const int kt = f >> 2, jt = f & 3;
        const int krow = kt * 16 + (l & 15);
        const int j0   = jt * 32 + ((l >> 4) << 3);
        const float4* wp = (const float4*)(w0 + krow * 128 + j0);
        const float4 a = wp[0], bq = wp[1];
        uint4 pk;
        pk.x = f2bf(a.x)  | (f2bf(a.y)  << 16);
        pk.y = f2bf(a.z)  | (f2bf(a.w)  << 16);
        pk.z = f2bf(bq.x) | (f2bf(bq.y) << 16);
        pk.w = f2bf(bq.z) | (f2bf(bq.w) << 16);
        *(uint4*)(w0sh + (size_t)c * 8) = pk;
    }

    // ---- stage h tile: 4 coalesced uint4 per thread ----
    #pragma unroll
    for (int it = 0; it < 4; ++it) {
        const int q   = it * 256 + tid;
        const int j   = q >> 3, sub = q & 7;
        const unsigned short* rp =
            hbuf + ((size_t)((j >> 6) * BB + b) * HH + (j & 63)) * TT + t0;
        const uint4 v = *(const uint4*)(rp + sub * 8);
        const int dwb = j * 32 + sub * 4;
        *(uint4*)(hsh + (dwb ^ (((j >> 3) & 3) << 3))) = v;
    }
    __syncthreads();

    const int lg = lane >> 4;                      // k-group 0..3
    const int tl = (wv << 4) + (lane & 15);        // t within tile
    const int t  = t0 + tl;                        // output column

    f32x4 acc[8];
    #pragma unroll
    for (int kt = 0; kt < 8; ++kt) {
        const float4 v = *(const float4*)(b0 + kt * 16 + lg * 4);
        acc[kt][0] = v.x; acc[kt][1] = v.y; acc[kt][2] = v.z; acc[kt][3] = v.w;
    }

    const unsigned short* hus = (const unsigned short*)hsh;
    #pragma unroll
    for (int jt = 0; jt < 4; ++jt) {
        bf16x8 bf;
        #pragma unroll
        for (int i = 0; i < 8; ++i) {
            const int j  = jt * 32 + lg * 8 + i;
            const int dw = (j * 32 + (tl >> 1)) ^ (lg << 3);
            bf[i] = (short)hus[dw * 2 + (tl & 1)];
        }
        #pragma unroll
        for (int kt = 0; kt < 8; ++kt) {
            const bf16x8 af = *(const bf16x8*)(w0sh + (size_t)((kt * 4 + jt) * 64 + lane) * 8);
            acc[kt] = __builtin_amdgcn_mfma_f32_16x16x32_bf16(af, bf, acc[kt], 0, 0, 0);
        }
    }

    float o = 0.0f;
    #pragma unroll
    for (int kt = 0; kt < 8; ++kt) {
        const float4 wq = *(const float4*)(w1 + kt * 16 + lg * 4);
        float v0 = acc[kt][0]; v0 = fmaxf(v0, 0.01f * v0); o = fmaf(v0, wq.x, o);
        float v1 = acc[kt][1]; v1 = fmaxf(v1, 0.01f * v1); o = fmaf(v1, wq.y, o);
        float v2 = acc[kt][2]; v2 = fmaxf(v2, 0.01f * v2); o = fmaf(v2, wq.z, o);
        float v3 = acc[kt][3]; v3 = fmaxf(v3, 0.01f * v3); o = fmaf(v3, wq.w, o);
    }
    o += __shfl_xor(o, 16);
    o += __shfl_xor(o, 32);
    if (lg == 0) out[(size_t)b * TT + t] = o + b1[0];
}

extern "C" void kernel_launch(void* const* d_in, const int* in_sizes, int n_in,
                              void* d_out, int out_size, void* d_ws, size_t ws_size,
                              hipStream_t stream) {
    (void)in_sizes; (void)n_in; (void)out_size; (void)ws_size;
    const float* x    = (const float*)d_in[0];
    const float* Wihf = (const float*)d_in[1];
    const float* Whhf = (const float*)d_in[2];
    const float* bihf = (const float*)d_in[3];
    const float* bhhf = (const float*)d_in[4];
    const float* Wihb = (const float*)d_in[5];
    const float* Whhb = (const float*)d_in[6];
    const float* bihb = (const float*)d_in[7];
    const float* bhhb = (const float*)d_in[8];
    const float* ff0w = (const float*)d_in[9];
    const float* ff0b = (const float*)d_in[10];
    const float* ff1w = (const float*)d_in[11];
    const float* ff1b = (const float*)d_in[12];
    unsigned short* hbuf = (unsigned short*)d_ws;   // [2][BB][HH][TT] bf16, 67 MB

    rnn_fused_kernel<<<dim3(16 * BB), dim3(512), 0, stream>>>(
        x, Wihf, bihf, bhhf, Wihb, bihb, bhhb, Whhf, Whhb, hbuf);
    mlp_kernel<<<dim3(BB * (TT / 64)), dim3(256), 0, stream>>>(
        hbuf, ff0w, ff0b, ff1w, ff1b, (float*)d_out);
}